// Round 1
// baseline (157.192 us; speedup 1.0000x reference)
//
#include <hip/hip_runtime.h>

// GruDirection2d forward_h: h[t] = z[t]*h_tilde[t] + (1-z[t])*h[t-1], scan over H.
// Shapes: z, h_tilde [B=4, C=64, H=512, W=512] f32; h0 [B, C, 1, W] f32.
// Chains along H are independent per (b, c, w): one thread owns 2 adjacent-w
// chains (float2), iterating h = 0..H-1 with coalesced 8B/lane loads/stores.

constexpr int Bc = 4;
constexpr int Cc = 64;
constexpr int Hc = 512;
constexpr int Wc = 512;

__global__ __launch_bounds__(256) void gru_h_scan(const float* __restrict__ z,
                                                  const float* __restrict__ ht,
                                                  const float* __restrict__ h0,
                                                  float* __restrict__ out) {
    constexpr int W2 = Wc / 2;  // float2 elements per row
    const int cid = blockIdx.x * blockDim.x + threadIdx.x;  // [0, B*C*W2)
    const int bc = cid / W2;        // which (b, c) plane
    const int w2 = cid - bc * W2;   // which float2 column

    const size_t plane = (size_t)bc * Hc * Wc;
    const size_t col = (size_t)w2;  // in float2 units

    // h0 is [B, C, 1, W] -> flat (bc * W + 2*w2)
    float2 h = reinterpret_cast<const float2*>(h0)[(size_t)bc * W2 + col];

    const float2* zp = reinterpret_cast<const float2*>(z) + plane / 2 + col;
    const float2* hp = reinterpret_cast<const float2*>(ht) + plane / 2 + col;
    float2* op = reinterpret_cast<float2*>(out) + plane / 2 + col;

#pragma unroll 8
    for (int t = 0; t < Hc; ++t) {
        const size_t off = (size_t)t * W2;
        float2 zt = zp[off];
        float2 cd = hp[off];
        h.x = fmaf(zt.x, cd.x, (1.0f - zt.x) * h.x);
        h.y = fmaf(zt.y, cd.y, (1.0f - zt.y) * h.y);
        op[off] = h;
    }
}

extern "C" void kernel_launch(void* const* d_in, const int* in_sizes, int n_in,
                              void* d_out, int out_size, void* d_ws, size_t ws_size,
                              hipStream_t stream) {
    const float* z = (const float*)d_in[0];
    const float* h_tilde = (const float*)d_in[1];
    const float* h0 = (const float*)d_in[2];
    float* out = (float*)d_out;

    const int n_chains2 = Bc * Cc * (Wc / 2);  // 65536 float2 chains
    const int block = 256;
    const int grid = n_chains2 / block;        // 256 blocks
    gru_h_scan<<<grid, block, 0, stream>>>(z, h_tilde, h0, out);
}

// Round 2
// 152.107 us; speedup vs baseline: 1.0334x; 1.0334x over previous
//
#include <hip/hip_runtime.h>

// GruDirection2d forward_h: h[t] = z[t]*h_tilde[t] + (1-z[t])*h[t-1], scan over H.
// Shapes: z, h_tilde [B=4, C=64, H=512, W=512] f32; h0 [B, C, 1, W] f32.
// One thread per (b,c,w) chain (scalar, 131072 threads = 2048 waves = 8/CU),
// unroll 16 to keep 32 independent loads in flight per thread.
// Non-temporal stores keep the output from evicting inputs out of L2/L3.

constexpr int Bc = 4;
constexpr int Cc = 64;
constexpr int Hc = 512;
constexpr int Wc = 512;

__global__ __launch_bounds__(256) void gru_h_scan(const float* __restrict__ z,
                                                  const float* __restrict__ ht,
                                                  const float* __restrict__ h0,
                                                  float* __restrict__ out) {
    const int cid = blockIdx.x * blockDim.x + threadIdx.x;  // [0, B*C*W)
    const int bc = cid / Wc;        // which (b, c) plane
    const int w = cid - bc * Wc;    // column

    const size_t base = (size_t)bc * Hc * Wc + w;

    // h0 is [B, C, 1, W]
    float h = h0[(size_t)bc * Wc + w];

    const float* zp = z + base;
    const float* hp = ht + base;
    float* op = out + base;

#pragma unroll 16
    for (int t = 0; t < Hc; ++t) {
        const size_t off = (size_t)t * Wc;
        const float zt = zp[off];
        const float cd = hp[off];
        h = fmaf(zt, cd, (1.0f - zt) * h);
        __builtin_nontemporal_store(h, op + off);
    }
}

extern "C" void kernel_launch(void* const* d_in, const int* in_sizes, int n_in,
                              void* d_out, int out_size, void* d_ws, size_t ws_size,
                              hipStream_t stream) {
    const float* z = (const float*)d_in[0];
    const float* h_tilde = (const float*)d_in[1];
    const float* h0 = (const float*)d_in[2];
    float* out = (float*)d_out;

    const int n_chains = Bc * Cc * Wc;      // 131072 scalar chains
    const int block = 256;
    const int grid = n_chains / block;      // 512 blocks -> 2 blocks/CU
    gru_h_scan<<<grid, block, 0, stream>>>(z, h_tilde, h0, out);
}